// Round 12
// baseline (315.028 us; speedup 1.0000x reference)
//
#include <hip/hip_runtime.h>
#include <math.h>

#define FFT_N 512

using half8 = __attribute__((ext_vector_type(8))) _Float16;
using half4 = __attribute__((ext_vector_type(4))) _Float16;
using f32x4 = __attribute__((ext_vector_type(4))) float;

// ================= Path 1: DFT-as-GEMM (needs 512 KB workspace) =========
// out[r][f] = sum_t x[r][t] * W[f][t],  W[f][t] = win[t]*cos(2*pi*t*f/512).
// Re(FFT) == cosine transform; window folded into W. fp16 operands, f32
// accumulate: max |err| ~0.04 << 0.125 tolerance.

// ---- Prologue: build W (512x512 fp16, row f, col t) into workspace ----
__global__ __launch_bounds__(128) void build_w_kernel(
        const float* __restrict__ win, _Float16* __restrict__ W) {
    const int f  = blockIdx.x;
    const int t0 = threadIdx.x * 4;
#pragma unroll
    for (int j = 0; j < 4; ++j) {
        const int t = t0 + j;
        const int m = (t * f) & 511;            // exact phase index mod 512
        const float c = cosf((float)m * (6.283185307179586f / 512.0f));
        W[f * 512 + t] = (_Float16)(win[t] * c);
    }
}

// ---- GEMM: M=65536, N=512, K=512; tile 128x128xK32; 4 waves (2x2) ----
// MFMA v_mfma_f32_16x16x32_f16. Lane maps (m89-verified family):
//   A-op: row = lane&15, k-slot = 8*(lane>>4)+j   (k-order cancels: both
//   B-op: col = lane&15, same k-slot               operands K-contiguous)
//   D   : row = 4*(lane>>4)+q, col = lane&15
#define BM 128
#define BN 128
#define BK 32

__global__ __launch_bounds__(256) void dft_gemm_kernel(
        const float* __restrict__ x,
        const _Float16* __restrict__ W,
        float* __restrict__ out) {
    __shared__ _Float16 Ah[BM][BK + 8];   // 40 halves = 80 B rows (pad: 16B-aligned, bank-spread)
    __shared__ _Float16 Bh[BN][BK + 8];

    const int tid  = threadIdx.x;
    const int lane = tid & 63;
    const int w    = tid >> 6;
    const int wm   = w >> 1;            // M-half of block tile
    const int wn   = w & 1;             // N-half
    const int l15  = lane & 15;
    const int l4   = lane >> 4;         // 0..3

    const int m_tile = (int)blockIdx.x >> 2;   // 4 N-siblings adjacent ->
    const int n_tile = (int)blockIdx.x & 3;    // A-panel L2/L3 locality
    const size_t bm = (size_t)m_tile * BM;
    const int    bn = n_tile * BN;

    // staging roles (uniform work: A 4xfloat4, B 2xfloat4 per thread)
    const int arow = tid >> 3;          // 0..31 (+32*i)
    const int aseg = tid & 7;           // 8 segs x 4 f32 = 32 cols
    const int brow = tid >> 1;          // 0..127
    const int bseg = tid & 1;           // segs {bseg, bseg+2} x 8 halves

    f32x4 acc[4][4];
#pragma unroll
    for (int mi = 0; mi < 4; ++mi)
#pragma unroll
        for (int ni = 0; ni < 4; ++ni)
            acc[mi][ni] = (f32x4){0.f, 0.f, 0.f, 0.f};

    float4 areg[4];
    float4 breg[2];

    // prefetch k-step 0
#pragma unroll
    for (int i = 0; i < 4; ++i)
        areg[i] = *(const float4*)(x + (bm + arow + 32 * i) * 512 + aseg * 4);
    breg[0] = *(const float4*)(W + (size_t)(bn + brow) * 512 + bseg * 8);
    breg[1] = *(const float4*)(W + (size_t)(bn + brow) * 512 + (bseg + 2) * 8);

    for (int s = 0; s < 16; ++s) {
        __syncthreads();   // WAR: previous step's fragment reads complete

        // commit staged regs to LDS (A: f32 -> fp16 cast)
#pragma unroll
        for (int i = 0; i < 4; ++i) {
            half4 h;
            h[0] = (_Float16)areg[i].x; h[1] = (_Float16)areg[i].y;
            h[2] = (_Float16)areg[i].z; h[3] = (_Float16)areg[i].w;
            *(half4*)&Ah[arow + 32 * i][aseg * 4] = h;
        }
        *(float4*)&Bh[brow][bseg * 8]       = breg[0];
        *(float4*)&Bh[brow][(bseg + 2) * 8] = breg[1];

        // prefetch next k-step (drains under the MFMA below)
        if (s + 1 < 16) {
            const int k0 = (s + 1) * BK;
#pragma unroll
            for (int i = 0; i < 4; ++i)
                areg[i] = *(const float4*)(x + (bm + arow + 32 * i) * 512 + k0 + aseg * 4);
            breg[0] = *(const float4*)(W + (size_t)(bn + brow) * 512 + k0 + bseg * 8);
            breg[1] = *(const float4*)(W + (size_t)(bn + brow) * 512 + k0 + (bseg + 2) * 8);
        }
        __syncthreads();   // LDS writes visible

        half8 af[4], bf[4];
#pragma unroll
        for (int mi = 0; mi < 4; ++mi)
            af[mi] = *(half8*)&Ah[wm * 64 + mi * 16 + l15][l4 * 8];
#pragma unroll
        for (int ni = 0; ni < 4; ++ni)
            bf[ni] = *(half8*)&Bh[wn * 64 + ni * 16 + l15][l4 * 8];
#pragma unroll
        for (int mi = 0; mi < 4; ++mi)
#pragma unroll
            for (int ni = 0; ni < 4; ++ni)
                acc[mi][ni] = __builtin_amdgcn_mfma_f32_16x16x32_f16(
                    af[mi], bf[ni], acc[mi][ni], 0, 0, 0);
    }

    // epilogue: D row = 4*l4+q, col = l15 (16 consecutive f32 per store group)
#pragma unroll
    for (int mi = 0; mi < 4; ++mi) {
        const size_t r0 = bm + wm * 64 + mi * 16 + l4 * 4;
#pragma unroll
        for (int q = 0; q < 4; ++q) {
            float* orow = out + (r0 + q) * 512 + bn + wn * 64 + l15;
#pragma unroll
            for (int ni = 0; ni < 4; ++ni)
                orow[ni * 16] = acc[mi][ni][q];
        }
    }
}

// ================= Path 2: fallback FFT (proven; used if ws too small) ===
#define LDS_STRIDE 576

#define WAVE_LDS_FENCE() do { \
    asm volatile("" ::: "memory"); \
    __builtin_amdgcn_wave_barrier(); \
    asm volatile("" ::: "memory"); \
} while (0)

__device__ __forceinline__ void fft8(float* re, float* im) {
    const float C = 0.70710678118654752440f;
    float tr[8], ti[8];
    tr[0]=re[0]+re[4]; ti[0]=im[0]+im[4];
    tr[4]=re[0]-re[4]; ti[4]=im[0]-im[4];
    tr[1]=re[1]+re[5]; ti[1]=im[1]+im[5];
    tr[5]=re[1]-re[5]; ti[5]=im[1]-im[5];
    tr[2]=re[2]+re[6]; ti[2]=im[2]+im[6];
    tr[6]=re[2]-re[6]; ti[6]=im[2]-im[6];
    tr[3]=re[3]+re[7]; ti[3]=im[3]+im[7];
    tr[7]=re[3]-re[7]; ti[7]=im[3]-im[7];
    { float a=tr[5], b=ti[5]; tr[5]=C*(a+b); ti[5]=C*(b-a); }
    { float a=tr[6], b=ti[6]; tr[6]=b;       ti[6]=-a;      }
    { float a=tr[7], b=ti[7]; tr[7]=C*(b-a); ti[7]=-C*(a+b);}
    {
        float s0r=tr[0]+tr[2], s0i=ti[0]+ti[2];
        float s2r=tr[0]-tr[2], s2i=ti[0]-ti[2];
        float s1r=tr[1]+tr[3], s1i=ti[1]+ti[3];
        float dr =tr[1]-tr[3], di =ti[1]-ti[3];
        float s3r= di, s3i=-dr;
        re[0]=s0r+s1r; im[0]=s0i+s1i;
        re[2]=s2r+s3r; im[2]=s2i+s3i;
        re[4]=s0r-s1r; im[4]=s0i-s1i;
        re[6]=s2r-s3r; im[6]=s2i-s3i;
    }
    {
        float s0r=tr[4]+tr[6], s0i=ti[4]+ti[6];
        float s2r=tr[4]-tr[6], s2i=ti[4]-ti[6];
        float s1r=tr[5]+tr[7], s1i=ti[5]+ti[7];
        float dr =tr[5]-tr[7], di =ti[5]-ti[7];
        float s3r= di, s3i=-dr;
        re[1]=s0r+s1r; im[1]=s0i+s1i;
        re[3]=s2r+s3r; im[3]=s2i+s3i;
        re[5]=s0r-s1r; im[5]=s0i-s1i;
        re[7]=s2r-s3r; im[7]=s2i-s3i;
    }
}

__device__ __forceinline__ void twiddle_chain(float* re, float* im,
                                              float c, float s) {
    float cr = c, ci = s;
#pragma unroll
    for (int k = 1; k < 8; ++k) {
        float a = re[k], b = im[k];
        re[k] = a * cr - b * ci;
        im[k] = a * ci + b * cr;
        float ncr = cr * c - ci * s;
        float nci = cr * s + ci * c;
        cr = ncr; ci = nci;
    }
}

__device__ __forceinline__ int swz3(int m) {
    return ((m ^ (m >> 2)) & 1)
         | (((m >> 3) & 7) << 1)
         | (((m >> 1) & 1) << 4)
         | (((m >> 2) & 1) << 5);
}

__global__ __launch_bounds__(64) void fft512_pack2_kernel(
        const float* __restrict__ x,
        const float* __restrict__ win,
        float* __restrict__ out) {
    __shared__ float2 L[LDS_STRIDE];
    const int lane = threadIdx.x & 63;
    const int pair = blockIdx.x;
    const int t4   = lane << 2;
    const int u    = lane & 15;
    const int pp   = lane >> 4;
    const int x0sw = (lane >> 2) & 3;
    const int l0r  = lane ^ pp;
    const int k1p  = lane >> 3;
    const int n3p  = lane & 7;
    const int rl   = (lane >> 3) | ((lane & 7) << 3);
    const int s3w  = swz3(rl);
    int sm[4], smm[4];
#pragma unroll
    for (int j = 0; j < 4; ++j) {
        const int m = 4 * u + j;
        sm[j]  = swz3(m);
        smm[j] = swz3((64 - m) & 63);
    }
    float cA, sA, cB, sB;
    __sincosf(-6.283185307179586f * (float)lane * (1.0f / 512.0f), &sA, &cA);
    __sincosf(-6.283185307179586f * (float)n3p  * (1.0f / 64.0f),  &sB, &cB);
    const float* __restrict__ x0 = x + (size_t)(2 * pair) * FFT_N;
    const float* __restrict__ x1 = x0 + FFT_N;
    const float4 w0  = *(const float4*)(win + t4);
    const float4 w1  = *(const float4*)(win + t4 + 256);
    const float4 xa0 = *(const float4*)(x0 + t4);
    const float4 xb0 = *(const float4*)(x1 + t4);
    const float4 xa1 = *(const float4*)(x0 + t4 + 256);
    const float4 xb1 = *(const float4*)(x1 + t4 + 256);
    {
        const float* a0 = (const float*)&xa0;
        const float* b0 = (const float*)&xb0;
        const float* a1 = (const float*)&xa1;
        const float* b1 = (const float*)&xb1;
        const float* W0 = (const float*)&w0;
        const float* W1 = (const float*)&w1;
#pragma unroll
        for (int j = 0; j < 4; ++j) {
            const int sl = j ^ x0sw;
            L[t4 +       sl] = make_float2(a0[j] * W0[j], b0[j] * W0[j]);
            L[t4 + 256 + sl] = make_float2(a1[j] * W1[j], b1[j] * W1[j]);
        }
    }
    WAVE_LDS_FENCE();
    float re[8], im[8];
#pragma unroll
    for (int n1 = 0; n1 < 8; ++n1) {
        float2 v = L[n1 * 64 + l0r];
        re[n1] = v.x; im[n1] = v.y;
    }
    WAVE_LDS_FENCE();
    fft8(re, im);
    twiddle_chain(re, im, cA, sA);
#pragma unroll
    for (int k1 = 0; k1 < 8; ++k1)
        L[k1 * 72 + lane] = make_float2(re[k1], im[k1]);
    WAVE_LDS_FENCE();
#pragma unroll
    for (int n2 = 0; n2 < 8; ++n2) {
        float2 v = L[k1p * 72 + n2 * 8 + n3p];
        re[n2] = v.x; im[n2] = v.y;
    }
    WAVE_LDS_FENCE();
    fft8(re, im);
    twiddle_chain(re, im, cB, sB);
#pragma unroll
    for (int k2 = 0; k2 < 8; ++k2)
        L[(k1p * 8 + k2) * 9 + n3p] = make_float2(re[k2], im[k2]);
    WAVE_LDS_FENCE();
#pragma unroll
    for (int n3 = 0; n3 < 8; ++n3) {
        float2 v = L[lane * 9 + n3];
        re[n3] = v.x; im[n3] = v.y;
    }
    WAVE_LDS_FENCE();
    fft8(re, im);
#pragma unroll
    for (int k3 = 0; k3 < 8; ++k3)
        L[(k3 << 6) + s3w] = make_float2(re[k3], im[k3]);
    WAVE_LDS_FENCE();
    float* __restrict__ o0 = out + (size_t)(2 * pair) * FFT_N;
    float* __restrict__ o1 = o0 + FFT_N;
#pragma unroll
    for (int half = 0; half < 2; ++half) {
        const int hk = 4 * half + pp;
        float4 ra, rb;
        float* pa = (float*)&ra;
        float* pb = (float*)&rb;
#pragma unroll
        for (int j = 0; j < 4; ++j) {
            const int m  = 4 * u + j;
            const int hn = ((512 - (hk << 6) - m) >> 6) & 7;
            const float2 zk = L[(hk << 6) + sm[j]];
            const float2 zn = L[(hn << 6) + smm[j]];
            pa[j] = 0.5f * (zk.x + zn.x);
            pb[j] = 0.5f * (zk.y + zn.y);
        }
        *(float4*)(o0 + 256 * half + t4) = ra;
        *(float4*)(o1 + 256 * half + t4) = rb;
    }
}

// ================= Host launch =================
extern "C" void kernel_launch(void* const* d_in, const int* in_sizes, int n_in,
                              void* d_out, int out_size, void* d_ws, size_t ws_size,
                              hipStream_t stream) {
    const float* x   = (const float*)d_in[0];
    const float* win = (const float*)d_in[1];
    float* out       = (float*)d_out;
    const int rows   = in_sizes[0] / FFT_N;              // 65536

    if (d_ws != nullptr && ws_size >= (size_t)512 * 512 * sizeof(_Float16)) {
        _Float16* W = (_Float16*)d_ws;
        hipLaunchKernelGGL(build_w_kernel, dim3(512), dim3(128), 0, stream,
                           win, W);
        const int blocks = (rows / BM) * (512 / BN);     // 512*4 = 2048
        hipLaunchKernelGGL(dft_gemm_kernel, dim3(blocks), dim3(256), 0, stream,
                           x, W, out);
    } else {
        const int pairs = rows / 2;                      // 32768
        hipLaunchKernelGGL(fft512_pack2_kernel, dim3(pairs), dim3(64), 0, stream,
                           x, win, out);
    }
}

// Round 13
// 307.966 us; speedup vs baseline: 1.0229x; 1.0229x over previous
//
#include <hip/hip_runtime.h>
#include <math.h>

#define FFT_N 512

using half8 = __attribute__((ext_vector_type(8))) _Float16;
using half4 = __attribute__((ext_vector_type(4))) _Float16;
using f32x4 = __attribute__((ext_vector_type(4))) float;

// ================= Path 1: DFT-as-GEMM (needs 512 KB workspace) =========
// out[r][f] = sum_t x[r][t] * W[f][t],  W[f][t] = win[t]*cos(2*pi*t*f/512).
// Re(FFT) == cosine transform; window folded into W. fp16 operands, f32
// accumulate (identical numerics to the R12 run that passed at absmax 0.25).

// ---- Prologue: build W (512x512 fp16, row f, col t) into workspace ----
__global__ __launch_bounds__(128) void build_w_kernel(
        const float* __restrict__ win, _Float16* __restrict__ W) {
    const int f  = blockIdx.x;
    const int t0 = threadIdx.x * 4;
#pragma unroll
    for (int j = 0; j < 4; ++j) {
        const int t = t0 + j;
        const int m = (t * f) & 511;            // exact phase index mod 512
        const float c = cosf((float)m * (6.283185307179586f / 512.0f));
        W[f * 512 + t] = (_Float16)(win[t] * c);
    }
}

// ---- GEMM: M=65536, N=512, K=512; tile 128x128xK32; 4 waves (2x2) ----
// MFMA v_mfma_f32_16x16x32_f16 (layout validated by R12's passing run).
#define BM 128
#define BN 128
#define BK 32

union SharedMem {
    struct {
        _Float16 Ah[BM][BK + 8];   // 10240 B
        _Float16 Bh[BN][BK + 8];   // 10240 B
    } s;                            // 20480 B staging
    float e[4][16][68];             // 17408 B epilogue transpose (per-wave 16x68)
};

__global__ __launch_bounds__(256) void dft_gemm_kernel(
        const float* __restrict__ x,
        const _Float16* __restrict__ W,
        float* __restrict__ out) {
    __shared__ SharedMem smem;

    const int tid  = threadIdx.x;
    const int lane = tid & 63;
    const int w    = tid >> 6;
    const int wm   = w >> 1;            // M-half of block tile
    const int wn   = w & 1;             // N-half
    const int l15  = lane & 15;
    const int l4   = lane >> 4;         // 0..3

    // XCD-aware remap: the 4 N-siblings of an M-panel share blockIdx%8
    // (same XCD L2), 8 apart in dispatch order -> A-panel L2 reuse.
    const int bx     = (int)blockIdx.x;
    const int xcd    = bx & 7;
    const int g      = bx >> 3;
    const int n_tile = g & 3;
    const int m_tile = (g >> 2) * 8 + xcd;       // 0..511
    const size_t bm  = (size_t)m_tile * BM;
    const int    bn  = n_tile * BN;

    // staging roles (A: 4x float4 of f32; B: 2x float4 = 16 halves)
    const int arow = tid >> 3;          // 0..31 (+32*i)
    const int aseg = tid & 7;           // 8 segs x 4 f32 = 32 cols
    const int brow = tid >> 1;          // 0..127
    const int bseg = tid & 1;           // segs {bseg, bseg+2} x 8 halves

    f32x4 acc[4][4];
#pragma unroll
    for (int mi = 0; mi < 4; ++mi)
#pragma unroll
        for (int ni = 0; ni < 4; ++ni)
            acc[mi][ni] = (f32x4){0.f, 0.f, 0.f, 0.f};

    float4 areg[4];
    float4 breg[2];

    // prefetch k-step 0
#pragma unroll
    for (int i = 0; i < 4; ++i)
        areg[i] = *(const float4*)(x + (bm + arow + 32 * i) * 512 + aseg * 4);
    breg[0] = *(const float4*)(W + (size_t)(bn + brow) * 512 + bseg * 8);
    breg[1] = *(const float4*)(W + (size_t)(bn + brow) * 512 + (bseg + 2) * 8);

    for (int s = 0; s < 16; ++s) {
        __syncthreads();   // WAR: previous step's fragment reads complete

        // commit staged regs to LDS (A: f32 -> fp16 cast)
#pragma unroll
        for (int i = 0; i < 4; ++i) {
            half4 h;
            h[0] = (_Float16)areg[i].x; h[1] = (_Float16)areg[i].y;
            h[2] = (_Float16)areg[i].z; h[3] = (_Float16)areg[i].w;
            *(half4*)&smem.s.Ah[arow + 32 * i][aseg * 4] = h;
        }
        *(float4*)&smem.s.Bh[brow][bseg * 8]       = breg[0];
        *(float4*)&smem.s.Bh[brow][(bseg + 2) * 8] = breg[1];

        // prefetch next k-step (drains under the MFMA below)
        if (s + 1 < 16) {
            const int k0 = (s + 1) * BK;
#pragma unroll
            for (int i = 0; i < 4; ++i)
                areg[i] = *(const float4*)(x + (bm + arow + 32 * i) * 512 + k0 + aseg * 4);
            breg[0] = *(const float4*)(W + (size_t)(bn + brow) * 512 + k0 + bseg * 8);
            breg[1] = *(const float4*)(W + (size_t)(bn + brow) * 512 + k0 + (bseg + 2) * 8);
        }
        __syncthreads();   // LDS writes visible

        half8 af[4], bf[4];
#pragma unroll
        for (int mi = 0; mi < 4; ++mi)
            af[mi] = *(half8*)&smem.s.Ah[wm * 64 + mi * 16 + l15][l4 * 8];
#pragma unroll
        for (int ni = 0; ni < 4; ++ni)
            bf[ni] = *(half8*)&smem.s.Bh[wn * 64 + ni * 16 + l15][l4 * 8];
#pragma unroll
        for (int mi = 0; mi < 4; ++mi)
#pragma unroll
            for (int ni = 0; ni < 4; ++ni)
                acc[mi][ni] = __builtin_amdgcn_mfma_f32_16x16x32_f16(
                    af[mi], bf[ni], acc[mi][ni], 0, 0, 0);
    }

    // ---- Epilogue: coalesced float4 stores via per-wave LDS transpose ----
    // D fragment: row = 4*l4+q, col = l15 (+16*ni). Scatter one mi-chunk
    // (16 rows x 64 cols) into wave-private e[w], re-read as float4 rows,
    // store 256 B per 16-lane phase (full cache lines; no RMW).
    __syncthreads();   // all fragment reads done before LDS is repurposed
#pragma unroll
    for (int mi = 0; mi < 4; ++mi) {
#pragma unroll
        for (int ni = 0; ni < 4; ++ni)
#pragma unroll
            for (int q = 0; q < 4; ++q)
                smem.e[w][l4 * 4 + q][ni * 16 + l15] = acc[mi][ni][q];
        // wave-private region: in-wave DS ordering + compiler fence suffice
        asm volatile("" ::: "memory");
        __builtin_amdgcn_wave_barrier();
        asm volatile("" ::: "memory");
#pragma unroll
        for (int j = 0; j < 4; ++j) {
            const int r = 4 * j + l4;                     // 0..15
            float4 v = *(const float4*)&smem.e[w][r][l15 * 4];
            float* dst = out + (bm + wm * 64 + mi * 16 + r) * 512
                             + bn + wn * 64 + l15 * 4;
            *(float4*)dst = v;
        }
        asm volatile("" ::: "memory");
        __builtin_amdgcn_wave_barrier();   // WAR before next mi-chunk reuse
        asm volatile("" ::: "memory");
    }
}

// ================= Path 2: fallback FFT (proven; used if ws too small) ===
#define LDS_STRIDE 576

#define WAVE_LDS_FENCE() do { \
    asm volatile("" ::: "memory"); \
    __builtin_amdgcn_wave_barrier(); \
    asm volatile("" ::: "memory"); \
} while (0)

__device__ __forceinline__ void fft8(float* re, float* im) {
    const float C = 0.70710678118654752440f;
    float tr[8], ti[8];
    tr[0]=re[0]+re[4]; ti[0]=im[0]+im[4];
    tr[4]=re[0]-re[4]; ti[4]=im[0]-im[4];
    tr[1]=re[1]+re[5]; ti[1]=im[1]+im[5];
    tr[5]=re[1]-re[5]; ti[5]=im[1]-im[5];
    tr[2]=re[2]+re[6]; ti[2]=im[2]+im[6];
    tr[6]=re[2]-re[6]; ti[6]=im[2]-im[6];
    tr[3]=re[3]+re[7]; ti[3]=im[3]+im[7];
    tr[7]=re[3]-re[7]; ti[7]=im[3]-im[7];
    { float a=tr[5], b=ti[5]; tr[5]=C*(a+b); ti[5]=C*(b-a); }
    { float a=tr[6], b=ti[6]; tr[6]=b;       ti[6]=-a;      }
    { float a=tr[7], b=ti[7]; tr[7]=C*(b-a); ti[7]=-C*(a+b);}
    {
        float s0r=tr[0]+tr[2], s0i=ti[0]+ti[2];
        float s2r=tr[0]-tr[2], s2i=ti[0]-ti[2];
        float s1r=tr[1]+tr[3], s1i=ti[1]+ti[3];
        float dr =tr[1]-tr[3], di =ti[1]-ti[3];
        float s3r= di, s3i=-dr;
        re[0]=s0r+s1r; im[0]=s0i+s1i;
        re[2]=s2r+s3r; im[2]=s2i+s3i;
        re[4]=s0r-s1r; im[4]=s0i-s1i;
        re[6]=s2r-s3r; im[6]=s2i-s3i;
    }
    {
        float s0r=tr[4]+tr[6], s0i=ti[4]+ti[6];
        float s2r=tr[4]-tr[6], s2i=ti[4]-ti[6];
        float s1r=tr[5]+tr[7], s1i=ti[5]+ti[7];
        float dr =tr[5]-tr[7], di =ti[5]-ti[7];
        float s3r= di, s3i=-dr;
        re[1]=s0r+s1r; im[1]=s0i+s1i;
        re[3]=s2r+s3r; im[3]=s2i+s3i;
        re[5]=s0r-s1r; im[5]=s0i-s1i;
        re[7]=s2r-s3r; im[7]=s2i-s3i;
    }
}

__device__ __forceinline__ void twiddle_chain(float* re, float* im,
                                              float c, float s) {
    float cr = c, ci = s;
#pragma unroll
    for (int k = 1; k < 8; ++k) {
        float a = re[k], b = im[k];
        re[k] = a * cr - b * ci;
        im[k] = a * ci + b * cr;
        float ncr = cr * c - ci * s;
        float nci = cr * s + ci * c;
        cr = ncr; ci = nci;
    }
}

__device__ __forceinline__ int swz3(int m) {
    return ((m ^ (m >> 2)) & 1)
         | (((m >> 3) & 7) << 1)
         | (((m >> 1) & 1) << 4)
         | (((m >> 2) & 1) << 5);
}

__global__ __launch_bounds__(64) void fft512_pack2_kernel(
        const float* __restrict__ x,
        const float* __restrict__ win,
        float* __restrict__ out) {
    __shared__ float2 L[LDS_STRIDE];
    const int lane = threadIdx.x & 63;
    const int pair = blockIdx.x;
    const int t4   = lane << 2;
    const int u    = lane & 15;
    const int pp   = lane >> 4;
    const int x0sw = (lane >> 2) & 3;
    const int l0r  = lane ^ pp;
    const int k1p  = lane >> 3;
    const int n3p  = lane & 7;
    const int rl   = (lane >> 3) | ((lane & 7) << 3);
    const int s3w  = swz3(rl);
    int sm[4], smm[4];
#pragma unroll
    for (int j = 0; j < 4; ++j) {
        const int m = 4 * u + j;
        sm[j]  = swz3(m);
        smm[j] = swz3((64 - m) & 63);
    }
    float cA, sA, cB, sB;
    __sincosf(-6.283185307179586f * (float)lane * (1.0f / 512.0f), &sA, &cA);
    __sincosf(-6.283185307179586f * (float)n3p  * (1.0f / 64.0f),  &sB, &cB);
    const float* __restrict__ x0 = x + (size_t)(2 * pair) * FFT_N;
    const float* __restrict__ x1 = x0 + FFT_N;
    const float4 w0  = *(const float4*)(win + t4);
    const float4 w1  = *(const float4*)(win + t4 + 256);
    const float4 xa0 = *(const float4*)(x0 + t4);
    const float4 xb0 = *(const float4*)(x1 + t4);
    const float4 xa1 = *(const float4*)(x0 + t4 + 256);
    const float4 xb1 = *(const float4*)(x1 + t4 + 256);
    {
        const float* a0 = (const float*)&xa0;
        const float* b0 = (const float*)&xb0;
        const float* a1 = (const float*)&xa1;
        const float* b1 = (const float*)&xb1;
        const float* W0 = (const float*)&w0;
        const float* W1 = (const float*)&w1;
#pragma unroll
        for (int j = 0; j < 4; ++j) {
            const int sl = j ^ x0sw;
            L[t4 +       sl] = make_float2(a0[j] * W0[j], b0[j] * W0[j]);
            L[t4 + 256 + sl] = make_float2(a1[j] * W1[j], b1[j] * W1[j]);
        }
    }
    WAVE_LDS_FENCE();
    float re[8], im[8];
#pragma unroll
    for (int n1 = 0; n1 < 8; ++n1) {
        float2 v = L[n1 * 64 + l0r];
        re[n1] = v.x; im[n1] = v.y;
    }
    WAVE_LDS_FENCE();
    fft8(re, im);
    twiddle_chain(re, im, cA, sA);
#pragma unroll
    for (int k1 = 0; k1 < 8; ++k1)
        L[k1 * 72 + lane] = make_float2(re[k1], im[k1]);
    WAVE_LDS_FENCE();
#pragma unroll
    for (int n2 = 0; n2 < 8; ++n2) {
        float2 v = L[k1p * 72 + n2 * 8 + n3p];
        re[n2] = v.x; im[n2] = v.y;
    }
    WAVE_LDS_FENCE();
    fft8(re, im);
    twiddle_chain(re, im, cB, sB);
#pragma unroll
    for (int k2 = 0; k2 < 8; ++k2)
        L[(k1p * 8 + k2) * 9 + n3p] = make_float2(re[k2], im[k2]);
    WAVE_LDS_FENCE();
#pragma unroll
    for (int n3 = 0; n3 < 8; ++n3) {
        float2 v = L[lane * 9 + n3];
        re[n3] = v.x; im[n3] = v.y;
    }
    WAVE_LDS_FENCE();
    fft8(re, im);
#pragma unroll
    for (int k3 = 0; k3 < 8; ++k3)
        L[(k3 << 6) + s3w] = make_float2(re[k3], im[k3]);
    WAVE_LDS_FENCE();
    float* __restrict__ o0 = out + (size_t)(2 * pair) * FFT_N;
    float* __restrict__ o1 = o0 + FFT_N;
#pragma unroll
    for (int half = 0; half < 2; ++half) {
        const int hk = 4 * half + pp;
        float4 ra, rb;
        float* pa = (float*)&ra;
        float* pb = (float*)&rb;
#pragma unroll
        for (int j = 0; j < 4; ++j) {
            const int m  = 4 * u + j;
            const int hn = ((512 - (hk << 6) - m) >> 6) & 7;
            const float2 zk = L[(hk << 6) + sm[j]];
            const float2 zn = L[(hn << 6) + smm[j]];
            pa[j] = 0.5f * (zk.x + zn.x);
            pb[j] = 0.5f * (zk.y + zn.y);
        }
        *(float4*)(o0 + 256 * half + t4) = ra;
        *(float4*)(o1 + 256 * half + t4) = rb;
    }
}

// ================= Host launch =================
extern "C" void kernel_launch(void* const* d_in, const int* in_sizes, int n_in,
                              void* d_out, int out_size, void* d_ws, size_t ws_size,
                              hipStream_t stream) {
    const float* x   = (const float*)d_in[0];
    const float* win = (const float*)d_in[1];
    float* out       = (float*)d_out;
    const int rows   = in_sizes[0] / FFT_N;              // 65536

    if (d_ws != nullptr && ws_size >= (size_t)512 * 512 * sizeof(_Float16)) {
        _Float16* W = (_Float16*)d_ws;
        hipLaunchKernelGGL(build_w_kernel, dim3(512), dim3(128), 0, stream,
                           win, W);
        const int blocks = (rows / BM) * (512 / BN);     // 512*4 = 2048
        hipLaunchKernelGGL(dft_gemm_kernel, dim3(blocks), dim3(256), 0, stream,
                           x, W, out);
    } else {
        const int pairs = rows / 2;                      // 32768
        hipLaunchKernelGGL(fft512_pack2_kernel, dim3(pairs), dim3(64), 0, stream,
                           x, win, out);
    }
}